// Round 6
// baseline (650.521 us; speedup 1.0000x reference)
//
#include <hip/hip_runtime.h>
#include <hip/hip_bf16.h>

typedef __hip_bfloat16 bf16;

#define N_NODES 100000
#define N_EDGES 1600000
#define IN_CH   128
#define ED_DIM  32
#define HEADS   4
#define C_OUT   32
#define HC      128   // HEADS * C_OUT
#define NEG_SLOPE 0.2f
#define SCAN_BLOCKS 98   // ceil(100000 / 1024)

__device__ __forceinline__ float bf_lo(unsigned u) { return __uint_as_float(u << 16); }
__device__ __forceinline__ float bf_hi(unsigned u) { return __uint_as_float(u & 0xffff0000u); }
__device__ __forceinline__ unsigned short f2bf_rne(float f) {
    unsigned u = __float_as_uint(f);
    return (unsigned short)((u + 0x7fffu + ((u >> 16) & 1u)) >> 16);
}
__device__ __forceinline__ unsigned pack_bf2(float a, float b) {
    return ((unsigned)f2bf_rne(b) << 16) | f2bf_rne(a);
}
__device__ __forceinline__ float load_any(const void* p, int i, int isf32) {
    return isf32 ? ((const float*)p)[i]
                 : __uint_as_float(((unsigned)((const unsigned short*)p)[i]) << 16);
}

// ---------------------------------------------------------------------------
// dtype detect (R4-verified: harness passes f32; kept for robustness)
// ---------------------------------------------------------------------------
__global__ void detect(const unsigned* __restrict__ xw, int* __restrict__ flag) {
    __shared__ int cnt;
    if (threadIdx.x == 0) cnt = 0;
    __syncthreads();
    unsigned w = xw[threadIdx.x];
    int e = (w >> 7) & 0xFF;
    if (e >= 140) atomicAdd(&cnt, 1);
    __syncthreads();
    if (threadIdx.x == 0) *flag = (cnt >= 32) ? 1 : 0;
}

__global__ void report_err(unsigned short* out, float code) {
    if (threadIdx.x < 16) out[threadIdx.x] = f2bf_rne(code);
}

__global__ __launch_bounds__(256) void zero_ints(int* __restrict__ p, int n) {
    int i = blockIdx.x * 256 + threadIdx.x;
    if (i < n) p[i] = 0;
}

// ---------------------------------------------------------------------------
// Canonicalize small tensors; Wa[h*32+d] = sum_c W_edge[d,h*32+c]*att_edge[h,c]
// ---------------------------------------------------------------------------
__global__ __launch_bounds__(256) void prep_small(
    const int* __restrict__ flag,
    const void* __restrict__ W, const void* __restrict__ att_src,
    const void* __restrict__ att_dst, const void* __restrict__ W_edge,
    const void* __restrict__ att_edge, const void* __restrict__ gat_bias,
    const void* __restrict__ bias,
    unsigned short* __restrict__ Wc, float* __restrict__ att_src_f,
    float* __restrict__ att_dst_f, float* __restrict__ gat_bias_f,
    float* __restrict__ bias_f, float* __restrict__ Wa) {

    int isf32 = *flag;
    int t = threadIdx.x;
    for (int i = t; i < IN_CH * HC; i += 256)
        Wc[i] = f2bf_rne(load_any(W, i, isf32));
    if (t < 128) {
        att_src_f[t]  = load_any(att_src, t, isf32);
        att_dst_f[t]  = load_any(att_dst, t, isf32);
        gat_bias_f[t] = load_any(gat_bias, t, isf32);
    }
    if (t < 32) bias_f[t] = load_any(bias, t, isf32);
    if (t < 128) {
        int d = t & 31, h = t >> 5;
        float acc = 0.f;
        for (int c = 0; c < C_OUT; ++c)
            acc += load_any(W_edge, d * HC + h * C_OUT + c, isf32) *
                   load_any(att_edge, h * C_OUT + c, isf32);
        Wa[h * 32 + d] = acc;
    }
}

// ---------------------------------------------------------------------------
// xh = x @ W, 32 nodes/block, 16 acc/thread; fused a_src/a_dst epilogue.
// ---------------------------------------------------------------------------
__global__ __launch_bounds__(256) void node_gemm(
    const int* __restrict__ flag, const void* __restrict__ x,
    const unsigned short* __restrict__ Wc,
    const float* __restrict__ att_src_f, const float* __restrict__ att_dst_f,
    unsigned short* __restrict__ xh,
    float* __restrict__ a_src, float* __restrict__ a_dst) {

    __shared__ unsigned short Wl[IN_CH * HC];   // 32 KB
    __shared__ float xl[32 * IN_CH];            // 16 KB

    int isf32 = *flag;
    int t = threadIdx.x;
    int node0 = blockIdx.x * 32;

    const uint4* Wg = (const uint4*)Wc;
    uint4* Wl4 = (uint4*)Wl;
#pragma unroll
    for (int k = 0; k < 8; ++k) Wl4[t + k * 256] = Wg[t + k * 256];

    if (isf32) {
        const float4* xg = (const float4*)((const float*)x + (size_t)node0 * IN_CH);
        float4* xl4 = (float4*)xl;
#pragma unroll
        for (int k = 0; k < 4; ++k) xl4[t + k * 256] = xg[t + k * 256];
    } else {
        const unsigned* xg = (const unsigned*)((const unsigned short*)x + (size_t)node0 * IN_CH);
#pragma unroll
        for (int k = 0; k < 8; ++k) {
            unsigned u = xg[t + k * 256];
            int f = 2 * (t + k * 256);
            xl[f]     = bf_lo(u);
            xl[f + 1] = bf_hi(u);
        }
    }
    __syncthreads();

    int q  = t & 31;
    int i0 = (t >> 5) * 4;
    int j4 = q * 4;
    float acc[16];
#pragma unroll
    for (int k = 0; k < 16; ++k) acc[k] = 0.f;

    const float* xr0 = xl + (i0 + 0) * IN_CH;
    const float* xr1 = xl + (i0 + 1) * IN_CH;
    const float* xr2 = xl + (i0 + 2) * IN_CH;
    const float* xr3 = xl + (i0 + 3) * IN_CH;

#pragma unroll 8
    for (int d = 0; d < IN_CH; ++d) {
        uint2 wb = *(const uint2*)(Wl + d * HC + j4);
        float w0 = bf_lo(wb.x), w1 = bf_hi(wb.x);
        float w2 = bf_lo(wb.y), w3 = bf_hi(wb.y);
        float x0 = xr0[d], x1 = xr1[d], x2 = xr2[d], x3 = xr3[d];
        acc[0]  += x0 * w0; acc[1]  += x0 * w1; acc[2]  += x0 * w2; acc[3]  += x0 * w3;
        acc[4]  += x1 * w0; acc[5]  += x1 * w1; acc[6]  += x1 * w2; acc[7]  += x1 * w3;
        acc[8]  += x2 * w0; acc[9]  += x2 * w1; acc[10] += x2 * w2; acc[11] += x2 * w3;
        acc[12] += x3 * w0; acc[13] += x3 * w1; acc[14] += x3 * w2; acc[15] += x3 * w3;
    }

    float4 sa = *(const float4*)(att_src_f + j4);
    float4 da = *(const float4*)(att_dst_f + j4);

#pragma unroll
    for (int k = 0; k < 4; ++k) {
        int node = node0 + i0 + k;
        float a0 = acc[4 * k], a1 = acc[4 * k + 1], a2 = acc[4 * k + 2], a3 = acc[4 * k + 3];
        *(uint2*)(xh + (size_t)node * HC + j4) =
            make_uint2(pack_bf2(a0, a1), pack_bf2(a2, a3));

        float ps = a0 * sa.x + a1 * sa.y + a2 * sa.z + a3 * sa.w;
        float pd = a0 * da.x + a1 * da.y + a2 * da.z + a3 * da.w;
        ps += __shfl_xor(ps, 1); ps += __shfl_xor(ps, 2); ps += __shfl_xor(ps, 4);
        pd += __shfl_xor(pd, 1); pd += __shfl_xor(pd, 2); pd += __shfl_xor(pd, 4);
        if ((q & 7) == 0) {
            int h = q >> 3;
            a_src[node * HEADS + h] = ps;
            a_dst[node * HEADS + h] = pd;
        }
    }
}

// ---------------------------------------------------------------------------
// edge_w: per-edge attention weights written COALESCED in edge order
// (bf16 x4 packed in uint2, 12.8 MB streaming) + fused dst histogram.
// All random-write traffic removed from this (heaviest-read) pass.
// ---------------------------------------------------------------------------
__global__ __launch_bounds__(256) void edge_w(
    const int* __restrict__ flag,
    const int* __restrict__ ei, const void* __restrict__ edge_attr,
    const float* __restrict__ a_src, const float* __restrict__ a_dst,
    const float* __restrict__ Wa,
    uint2* __restrict__ w4b, int* __restrict__ count) {

    __shared__ float WaL[128];
    int t = threadIdx.x;
    if (t < 128) WaL[t] = Wa[t];
    __syncthreads();

    int isf32 = *flag;
    int e = blockIdx.x * 256 + t;
    if (e >= N_EDGES) return;
    int s  = ei[e];
    int dn = ei[N_EDGES + e];

    atomicAdd(&count[dn], 1);   // fused hist (fire-and-forget int atomic)

    float ae0 = 0.f, ae1 = 0.f, ae2 = 0.f, ae3 = 0.f;
    if (isf32) {
        const float4* ea = (const float4*)((const float*)edge_attr + (size_t)e * ED_DIM);
#pragma unroll
        for (int k = 0; k < 8; ++k) {
            float4 v = ea[k];
            int d = 4 * k;
            ae0 += v.x * WaL[d] + v.y * WaL[d + 1] + v.z * WaL[d + 2] + v.w * WaL[d + 3];
            ae1 += v.x * WaL[32 + d] + v.y * WaL[33 + d] + v.z * WaL[34 + d] + v.w * WaL[35 + d];
            ae2 += v.x * WaL[64 + d] + v.y * WaL[65 + d] + v.z * WaL[66 + d] + v.w * WaL[67 + d];
            ae3 += v.x * WaL[96 + d] + v.y * WaL[97 + d] + v.z * WaL[98 + d] + v.w * WaL[99 + d];
        }
    } else {
        const uint4* ea = (const uint4*)((const unsigned short*)edge_attr + (size_t)e * ED_DIM);
#pragma unroll
        for (int k = 0; k < 4; ++k) {
            uint4 v = ea[k];
            float g0 = bf_lo(v.x), g1 = bf_hi(v.x), g2 = bf_lo(v.y), g3 = bf_hi(v.y);
            float g4 = bf_lo(v.z), g5 = bf_hi(v.z), g6 = bf_lo(v.w), g7 = bf_hi(v.w);
            int d = 8 * k;
            ae0 += g0*WaL[d] + g1*WaL[d+1] + g2*WaL[d+2] + g3*WaL[d+3]
                 + g4*WaL[d+4] + g5*WaL[d+5] + g6*WaL[d+6] + g7*WaL[d+7];
            ae1 += g0*WaL[32+d] + g1*WaL[33+d] + g2*WaL[34+d] + g3*WaL[35+d]
                 + g4*WaL[36+d] + g5*WaL[37+d] + g6*WaL[38+d] + g7*WaL[39+d];
            ae2 += g0*WaL[64+d] + g1*WaL[65+d] + g2*WaL[66+d] + g3*WaL[67+d]
                 + g4*WaL[68+d] + g5*WaL[69+d] + g6*WaL[70+d] + g7*WaL[71+d];
            ae3 += g0*WaL[96+d] + g1*WaL[97+d] + g2*WaL[98+d] + g3*WaL[99+d]
                 + g4*WaL[100+d] + g5*WaL[101+d] + g6*WaL[102+d] + g7*WaL[103+d];
        }
    }

    float4 as = *(const float4*)(a_src + (size_t)s * 4);
    float4 ad = *(const float4*)(a_dst + (size_t)dn * 4);
    float l0 = as.x + ad.x + ae0;
    float l1 = as.y + ad.y + ae1;
    float l2 = as.z + ad.z + ae2;
    float l3 = as.w + ad.w + ae3;
    l0 = (l0 >= 0.f) ? l0 : NEG_SLOPE * l0;
    l1 = (l1 >= 0.f) ? l1 : NEG_SLOPE * l1;
    l2 = (l2 >= 0.f) ? l2 : NEG_SLOPE * l2;
    l3 = (l3 >= 0.f) ? l3 : NEG_SLOPE * l3;
    // logits O(1): unnormalized exp safe; ratio is exact softmax
    float w0 = __expf(l0), w1 = __expf(l1), w2 = __expf(l2), w3 = __expf(l3);

    w4b[e] = make_uint2(pack_bf2(w0, w1), pack_bf2(w2, w3));
}

// ---------------------------------------------------------------------------
// exclusive prefix sum over count[] -> starts[], cursor[]
// ---------------------------------------------------------------------------
__global__ __launch_bounds__(256) void scan_a(const int* __restrict__ count,
                                              int* __restrict__ starts,
                                              int* __restrict__ blockSums) {
    __shared__ int sd[256];
    int t = threadIdx.x;
    int base = blockIdx.x * 1024 + t * 4;
    int c0 = (base + 0 < N_NODES) ? count[base + 0] : 0;
    int c1 = (base + 1 < N_NODES) ? count[base + 1] : 0;
    int c2 = (base + 2 < N_NODES) ? count[base + 2] : 0;
    int c3 = (base + 3 < N_NODES) ? count[base + 3] : 0;
    int s = c0 + c1 + c2 + c3;
    sd[t] = s;
    __syncthreads();
    for (int off = 1; off < 256; off <<= 1) {
        int v = (t >= off) ? sd[t - off] : 0;
        __syncthreads();
        sd[t] += v;
        __syncthreads();
    }
    int excl = sd[t] - s;
    if (base + 0 < N_NODES) starts[base + 0] = excl;
    if (base + 1 < N_NODES) starts[base + 1] = excl + c0;
    if (base + 2 < N_NODES) starts[base + 2] = excl + c0 + c1;
    if (base + 3 < N_NODES) starts[base + 3] = excl + c0 + c1 + c2;
    if (t == 255) blockSums[blockIdx.x] = sd[255];
}

__global__ __launch_bounds__(128) void scan_b(int* __restrict__ blockSums) {
    __shared__ int sd[128];
    int t = threadIdx.x;
    int v = (t < SCAN_BLOCKS) ? blockSums[t] : 0;
    sd[t] = v;
    __syncthreads();
    for (int off = 1; off < 128; off <<= 1) {
        int u = (t >= off) ? sd[t - off] : 0;
        __syncthreads();
        sd[t] += u;
        __syncthreads();
    }
    if (t < SCAN_BLOCKS) blockSums[t] = sd[t] - v;   // exclusive
}

__global__ __launch_bounds__(256) void scan_c(int* __restrict__ starts,
                                              int* __restrict__ cursor,
                                              const int* __restrict__ blockSums) {
    int off = blockSums[blockIdx.x];
    int base = blockIdx.x * 1024 + threadIdx.x * 4;
#pragma unroll
    for (int k = 0; k < 4; ++k) {
        int idx = base + k;
        if (idx < N_NODES) {
            int v = starts[idx] + off;
            starts[idx] = v;
            cursor[idx] = v;
        }
    }
    if (blockIdx.x == 0 && threadIdx.x == 0) starts[N_NODES] = N_EDGES;
}

// ---------------------------------------------------------------------------
// build_perm: single 8B (src, edge-id) random store per edge — one cache
// line per edge instead of R5's two (perm_src 4B + perm_w 16B arrays).
// ---------------------------------------------------------------------------
__global__ __launch_bounds__(256) void build_perm(
    const int* __restrict__ ei, int* __restrict__ cursor,
    uint2* __restrict__ perm_se) {
    int e = blockIdx.x * 256 + threadIdx.x;
    if (e >= N_EDGES) return;
    int s  = ei[e];
    int dn = ei[N_EDGES + e];
    int pos = atomicAdd(&cursor[dn], 1);
    perm_se[pos] = make_uint2((unsigned)s, (unsigned)e);
}

// ---------------------------------------------------------------------------
// gather v3: wave per node. Stage (src,e) coalesced; staging lanes fetch
// w4b[e] (8B random, L2/L3-resident, 64 independent loads in flight) into
// LDS; inner unroll-4 loop does the xh row gathers.
// ---------------------------------------------------------------------------
__global__ __launch_bounds__(256) void gather(
    const int* __restrict__ flag,
    const int* __restrict__ starts, const uint2* __restrict__ perm_se,
    const uint2* __restrict__ w4b, const unsigned short* __restrict__ xh,
    const float* __restrict__ gat_bias_f, const float* __restrict__ bias_f,
    void* __restrict__ out) {

    __shared__ int  sS[4][64];
    __shared__ uint2 sW[4][64];

    int t = threadIdx.x;
    int w = t >> 6, lane = t & 63, h = lane >> 4;
    int n = blockIdx.x * 4 + w;
    if (n >= N_NODES) return;
    int isf32 = *flag;

    int st = starts[n], en = starts[n + 1];
    float f0 = 0.f, f1 = 0.f, wsum = 0.f;

    for (int base = st; base < en; base += 64) {
        int cnt = en - base;
        if (cnt > 64) cnt = 64;
        __builtin_amdgcn_wave_barrier();
        if (lane < cnt) {
            uint2 se = perm_se[base + lane];
            sS[w][lane] = (int)se.x;
            sW[w][lane] = w4b[se.y];
        }
        __builtin_amdgcn_wave_barrier();
#pragma unroll 4
        for (int jj = 0; jj < cnt; ++jj) {
            int s = sS[w][jj];
            uint2 wb = sW[w][jj];
            unsigned hw = (h & 2) ? wb.y : wb.x;
            float wt = (h & 1) ? bf_hi(hw) : bf_lo(hw);
            unsigned xv = *(const unsigned*)(xh + ((size_t)s << 7) + 2 * lane);
            f0 += wt * bf_lo(xv);
            f1 += wt * bf_hi(xv);
            wsum += wt;
        }
    }

    float inv = (wsum > 0.f) ? 1.f / wsum : 0.f;
    float v0 = f0 * inv + gat_bias_f[2 * lane];
    float v1 = f1 * inv + gat_bias_f[2 * lane + 1];
    v0 += __shfl_xor(v0, 16); v0 += __shfl_xor(v0, 32);
    v1 += __shfl_xor(v1, 16); v1 += __shfl_xor(v1, 32);

    if (lane < 16) {
        int c = 2 * lane;
        float o0 = fmaxf(v0 * 0.25f + bias_f[c],     0.f);
        float o1 = fmaxf(v1 * 0.25f + bias_f[c + 1], 0.f);
        if (isf32) {
            *(float2*)((float*)out + (size_t)n * C_OUT + c) = make_float2(o0, o1);
        } else {
            unsigned p = ((unsigned)f2bf_rne(o1) << 16) | f2bf_rne(o0);
            *(unsigned*)((unsigned short*)out + (size_t)n * C_OUT + c) = p;
        }
    }
}

// ---------------------------------------------------------------------------
extern "C" void kernel_launch(void* const* d_in, const int* in_sizes, int n_in,
                              void* d_out, int out_size, void* d_ws, size_t ws_size,
                              hipStream_t stream) {
    const void* x         = d_in[0];
    const int*  ei        = (const int*)d_in[1];
    const void* edge_attr = d_in[2];
    const void* W         = d_in[3];
    const void* att_src   = d_in[4];
    const void* att_dst   = d_in[5];
    const void* W_edge    = d_in[6];
    const void* att_edge  = d_in[7];
    const void* gat_bias  = d_in[8];
    const void* bias      = d_in[9];

    char* ws = (char*)d_ws;
    size_t off = 0;
    auto align256 = [](size_t v) { return (v + 255) & ~(size_t)255; };

    unsigned short* xh = (unsigned short*)(ws + off);
    off = align256(off + (size_t)N_NODES * HC * sizeof(unsigned short));  // 25.6 MB
    float* a_src_w = (float*)(ws + off);
    off = align256(off + (size_t)N_NODES * HEADS * sizeof(float));
    float* a_dst_w = (float*)(ws + off);
    off = align256(off + (size_t)N_NODES * HEADS * sizeof(float));
    int* count = (int*)(ws + off);
    off = align256(off + (size_t)N_NODES * sizeof(int));
    int* starts = (int*)(ws + off);
    off = align256(off + (size_t)(N_NODES + 1) * sizeof(int));
    int* cursor = (int*)(ws + off);
    off = align256(off + (size_t)N_NODES * sizeof(int));
    int* blockSums = (int*)(ws + off);
    off = align256(off + (size_t)SCAN_BLOCKS * sizeof(int));
    uint2* w4b = (uint2*)(ws + off);
    off = align256(off + (size_t)N_EDGES * sizeof(uint2));                // 12.8 MB
    uint2* perm_se = (uint2*)(ws + off);
    off = align256(off + (size_t)N_EDGES * sizeof(uint2));                // 12.8 MB
    float* Wa = (float*)(ws + off);
    off = align256(off + 128 * sizeof(float));
    unsigned short* Wc = (unsigned short*)(ws + off);
    off = align256(off + (size_t)IN_CH * HC * sizeof(unsigned short));
    float* att_src_f = (float*)(ws + off);
    off = align256(off + 128 * sizeof(float));
    float* att_dst_f = (float*)(ws + off);
    off = align256(off + 128 * sizeof(float));
    float* gat_bias_f = (float*)(ws + off);
    off = align256(off + 128 * sizeof(float));
    float* bias_f = (float*)(ws + off);
    off = align256(off + 32 * sizeof(float));
    int* dflag = (int*)(ws + off);
    off = align256(off + sizeof(int));
    size_t need = off;

    if (ws_size < need) {
        report_err<<<1, 64, 0, stream>>>((unsigned short*)d_out, 1500.0f);
        return;
    }

    (void)hipGetLastError();

    detect<<<1, 256, 0, stream>>>((const unsigned*)x, dflag);
    prep_small<<<1, 256, 0, stream>>>(dflag, W, att_src, att_dst, W_edge,
                                      att_edge, gat_bias, bias,
                                      Wc, att_src_f, att_dst_f, gat_bias_f,
                                      bias_f, Wa);
    zero_ints<<<(N_NODES + 255) / 256, 256, 0, stream>>>(count, N_NODES);
    node_gemm<<<N_NODES / 32, 256, 0, stream>>>(dflag, x, Wc, att_src_f,
                                                att_dst_f, xh, a_src_w, a_dst_w);
    edge_w<<<(N_EDGES + 255) / 256, 256, 0, stream>>>(dflag, ei, edge_attr,
                                                      a_src_w, a_dst_w, Wa,
                                                      w4b, count);
    scan_a<<<SCAN_BLOCKS, 256, 0, stream>>>(count, starts, blockSums);
    scan_b<<<1, 128, 0, stream>>>(blockSums);
    scan_c<<<SCAN_BLOCKS, 256, 0, stream>>>(starts, cursor, blockSums);
    build_perm<<<(N_EDGES + 255) / 256, 256, 0, stream>>>(ei, cursor, perm_se);
    gather<<<N_NODES / 4, 256, 0, stream>>>(dflag, starts, perm_se, w4b,
                                            xh, gat_bias_f, bias_f, d_out);

    hipError_t e = hipGetLastError();
    if (e != hipSuccess) {
        report_err<<<1, 64, 0, stream>>>((unsigned short*)d_out,
                                         1000.0f + (float)(int)e);
    }
}

// Round 7
// 598.433 us; speedup vs baseline: 1.0870x; 1.0870x over previous
//
#include <hip/hip_runtime.h>
#include <hip/hip_bf16.h>

typedef __hip_bfloat16 bf16;

#define N_NODES 100000
#define N_EDGES 1600000
#define IN_CH   128
#define ED_DIM  32
#define HEADS   4
#define C_OUT   32
#define HC      128   // HEADS * C_OUT
#define NEG_SLOPE 0.2f
#define SCAN_BLOCKS 98     // ceil(100000 / 1024)
#define BP_SLICES 8        // dst-space slices == XCD count
#define BP_SLICE_N 12500   // N_NODES / BP_SLICES
#define BP_CHUNKS 6250     // ceil(N_EDGES / 256)

__device__ __forceinline__ float bf_lo(unsigned u) { return __uint_as_float(u << 16); }
__device__ __forceinline__ float bf_hi(unsigned u) { return __uint_as_float(u & 0xffff0000u); }
__device__ __forceinline__ unsigned short f2bf_rne(float f) {
    unsigned u = __float_as_uint(f);
    return (unsigned short)((u + 0x7fffu + ((u >> 16) & 1u)) >> 16);
}
__device__ __forceinline__ unsigned pack_bf2(float a, float b) {
    return ((unsigned)f2bf_rne(b) << 16) | f2bf_rne(a);
}
__device__ __forceinline__ float load_any(const void* p, int i, int isf32) {
    return isf32 ? ((const float*)p)[i]
                 : __uint_as_float(((unsigned)((const unsigned short*)p)[i]) << 16);
}

// ---------------------------------------------------------------------------
// dtype detect (R4-verified: harness passes f32; kept for robustness)
// ---------------------------------------------------------------------------
__global__ void detect(const unsigned* __restrict__ xw, int* __restrict__ flag) {
    __shared__ int cnt;
    if (threadIdx.x == 0) cnt = 0;
    __syncthreads();
    unsigned w = xw[threadIdx.x];
    int e = (w >> 7) & 0xFF;
    if (e >= 140) atomicAdd(&cnt, 1);
    __syncthreads();
    if (threadIdx.x == 0) *flag = (cnt >= 32) ? 1 : 0;
}

__global__ void report_err(unsigned short* out, float code) {
    if (threadIdx.x < 16) out[threadIdx.x] = f2bf_rne(code);
}

__global__ __launch_bounds__(256) void zero_ints(int* __restrict__ p, int n) {
    int i = blockIdx.x * 256 + threadIdx.x;
    if (i < n) p[i] = 0;
}

// ---------------------------------------------------------------------------
// Canonicalize small tensors; Wa[h*32+d] = sum_c W_edge[d,h*32+c]*att_edge[h,c]
// ---------------------------------------------------------------------------
__global__ __launch_bounds__(256) void prep_small(
    const int* __restrict__ flag,
    const void* __restrict__ W, const void* __restrict__ att_src,
    const void* __restrict__ att_dst, const void* __restrict__ W_edge,
    const void* __restrict__ att_edge, const void* __restrict__ gat_bias,
    const void* __restrict__ bias,
    unsigned short* __restrict__ Wc, float* __restrict__ att_src_f,
    float* __restrict__ att_dst_f, float* __restrict__ gat_bias_f,
    float* __restrict__ bias_f, float* __restrict__ Wa) {

    int isf32 = *flag;
    int t = threadIdx.x;
    for (int i = t; i < IN_CH * HC; i += 256)
        Wc[i] = f2bf_rne(load_any(W, i, isf32));
    if (t < 128) {
        att_src_f[t]  = load_any(att_src, t, isf32);
        att_dst_f[t]  = load_any(att_dst, t, isf32);
        gat_bias_f[t] = load_any(gat_bias, t, isf32);
    }
    if (t < 32) bias_f[t] = load_any(bias, t, isf32);
    if (t < 128) {
        int d = t & 31, h = t >> 5;
        float acc = 0.f;
        for (int c = 0; c < C_OUT; ++c)
            acc += load_any(W_edge, d * HC + h * C_OUT + c, isf32) *
                   load_any(att_edge, h * C_OUT + c, isf32);
        Wa[h * 32 + d] = acc;
    }
}

// ---------------------------------------------------------------------------
// xh = x @ W, 32 nodes/block, 16 acc/thread; fused a_src/a_dst epilogue.
// ---------------------------------------------------------------------------
__global__ __launch_bounds__(256) void node_gemm(
    const int* __restrict__ flag, const void* __restrict__ x,
    const unsigned short* __restrict__ Wc,
    const float* __restrict__ att_src_f, const float* __restrict__ att_dst_f,
    unsigned short* __restrict__ xh,
    float* __restrict__ a_src, float* __restrict__ a_dst) {

    __shared__ unsigned short Wl[IN_CH * HC];   // 32 KB
    __shared__ float xl[32 * IN_CH];            // 16 KB

    int isf32 = *flag;
    int t = threadIdx.x;
    int node0 = blockIdx.x * 32;

    const uint4* Wg = (const uint4*)Wc;
    uint4* Wl4 = (uint4*)Wl;
#pragma unroll
    for (int k = 0; k < 8; ++k) Wl4[t + k * 256] = Wg[t + k * 256];

    if (isf32) {
        const float4* xg = (const float4*)((const float*)x + (size_t)node0 * IN_CH);
        float4* xl4 = (float4*)xl;
#pragma unroll
        for (int k = 0; k < 4; ++k) xl4[t + k * 256] = xg[t + k * 256];
    } else {
        const unsigned* xg = (const unsigned*)((const unsigned short*)x + (size_t)node0 * IN_CH);
#pragma unroll
        for (int k = 0; k < 8; ++k) {
            unsigned u = xg[t + k * 256];
            int f = 2 * (t + k * 256);
            xl[f]     = bf_lo(u);
            xl[f + 1] = bf_hi(u);
        }
    }
    __syncthreads();

    int q  = t & 31;
    int i0 = (t >> 5) * 4;
    int j4 = q * 4;
    float acc[16];
#pragma unroll
    for (int k = 0; k < 16; ++k) acc[k] = 0.f;

    const float* xr0 = xl + (i0 + 0) * IN_CH;
    const float* xr1 = xl + (i0 + 1) * IN_CH;
    const float* xr2 = xl + (i0 + 2) * IN_CH;
    const float* xr3 = xl + (i0 + 3) * IN_CH;

#pragma unroll 8
    for (int d = 0; d < IN_CH; ++d) {
        uint2 wb = *(const uint2*)(Wl + d * HC + j4);
        float w0 = bf_lo(wb.x), w1 = bf_hi(wb.x);
        float w2 = bf_lo(wb.y), w3 = bf_hi(wb.y);
        float x0 = xr0[d], x1 = xr1[d], x2 = xr2[d], x3 = xr3[d];
        acc[0]  += x0 * w0; acc[1]  += x0 * w1; acc[2]  += x0 * w2; acc[3]  += x0 * w3;
        acc[4]  += x1 * w0; acc[5]  += x1 * w1; acc[6]  += x1 * w2; acc[7]  += x1 * w3;
        acc[8]  += x2 * w0; acc[9]  += x2 * w1; acc[10] += x2 * w2; acc[11] += x2 * w3;
        acc[12] += x3 * w0; acc[13] += x3 * w1; acc[14] += x3 * w2; acc[15] += x3 * w3;
    }

    float4 sa = *(const float4*)(att_src_f + j4);
    float4 da = *(const float4*)(att_dst_f + j4);

#pragma unroll
    for (int k = 0; k < 4; ++k) {
        int node = node0 + i0 + k;
        float a0 = acc[4 * k], a1 = acc[4 * k + 1], a2 = acc[4 * k + 2], a3 = acc[4 * k + 3];
        *(uint2*)(xh + (size_t)node * HC + j4) =
            make_uint2(pack_bf2(a0, a1), pack_bf2(a2, a3));

        float ps = a0 * sa.x + a1 * sa.y + a2 * sa.z + a3 * sa.w;
        float pd = a0 * da.x + a1 * da.y + a2 * da.z + a3 * da.w;
        ps += __shfl_xor(ps, 1); ps += __shfl_xor(ps, 2); ps += __shfl_xor(ps, 4);
        pd += __shfl_xor(pd, 1); pd += __shfl_xor(pd, 2); pd += __shfl_xor(pd, 4);
        if ((q & 7) == 0) {
            int h = q >> 3;
            a_src[node * HEADS + h] = ps;
            a_dst[node * HEADS + h] = pd;
        }
    }
}

// ---------------------------------------------------------------------------
// edge_w: per-edge attention weights, COALESCED write (bf16 x4 in uint2,
// 12.8 MB streaming) + fused dst histogram.
// ---------------------------------------------------------------------------
__global__ __launch_bounds__(256) void edge_w(
    const int* __restrict__ flag,
    const int* __restrict__ ei, const void* __restrict__ edge_attr,
    const float* __restrict__ a_src, const float* __restrict__ a_dst,
    const float* __restrict__ Wa,
    uint2* __restrict__ w4b, int* __restrict__ count) {

    __shared__ float WaL[128];
    int t = threadIdx.x;
    if (t < 128) WaL[t] = Wa[t];
    __syncthreads();

    int isf32 = *flag;
    int e = blockIdx.x * 256 + t;
    if (e >= N_EDGES) return;
    int s  = ei[e];
    int dn = ei[N_EDGES + e];

    atomicAdd(&count[dn], 1);   // fused hist

    float ae0 = 0.f, ae1 = 0.f, ae2 = 0.f, ae3 = 0.f;
    if (isf32) {
        const float4* ea = (const float4*)((const float*)edge_attr + (size_t)e * ED_DIM);
#pragma unroll
        for (int k = 0; k < 8; ++k) {
            float4 v = ea[k];
            int d = 4 * k;
            ae0 += v.x * WaL[d] + v.y * WaL[d + 1] + v.z * WaL[d + 2] + v.w * WaL[d + 3];
            ae1 += v.x * WaL[32 + d] + v.y * WaL[33 + d] + v.z * WaL[34 + d] + v.w * WaL[35 + d];
            ae2 += v.x * WaL[64 + d] + v.y * WaL[65 + d] + v.z * WaL[66 + d] + v.w * WaL[67 + d];
            ae3 += v.x * WaL[96 + d] + v.y * WaL[97 + d] + v.z * WaL[98 + d] + v.w * WaL[99 + d];
        }
    } else {
        const uint4* ea = (const uint4*)((const unsigned short*)edge_attr + (size_t)e * ED_DIM);
#pragma unroll
        for (int k = 0; k < 4; ++k) {
            uint4 v = ea[k];
            float g0 = bf_lo(v.x), g1 = bf_hi(v.x), g2 = bf_lo(v.y), g3 = bf_hi(v.y);
            float g4 = bf_lo(v.z), g5 = bf_hi(v.z), g6 = bf_lo(v.w), g7 = bf_hi(v.w);
            int d = 8 * k;
            ae0 += g0*WaL[d] + g1*WaL[d+1] + g2*WaL[d+2] + g3*WaL[d+3]
                 + g4*WaL[d+4] + g5*WaL[d+5] + g6*WaL[d+6] + g7*WaL[d+7];
            ae1 += g0*WaL[32+d] + g1*WaL[33+d] + g2*WaL[34+d] + g3*WaL[35+d]
                 + g4*WaL[36+d] + g5*WaL[37+d] + g6*WaL[38+d] + g7*WaL[39+d];
            ae2 += g0*WaL[64+d] + g1*WaL[65+d] + g2*WaL[66+d] + g3*WaL[67+d]
                 + g4*WaL[68+d] + g5*WaL[69+d] + g6*WaL[70+d] + g7*WaL[71+d];
            ae3 += g0*WaL[96+d] + g1*WaL[97+d] + g2*WaL[98+d] + g3*WaL[99+d]
                 + g4*WaL[100+d] + g5*WaL[101+d] + g6*WaL[102+d] + g7*WaL[103+d];
        }
    }

    float4 as = *(const float4*)(a_src + (size_t)s * 4);
    float4 ad = *(const float4*)(a_dst + (size_t)dn * 4);
    float l0 = as.x + ad.x + ae0;
    float l1 = as.y + ad.y + ae1;
    float l2 = as.z + ad.z + ae2;
    float l3 = as.w + ad.w + ae3;
    l0 = (l0 >= 0.f) ? l0 : NEG_SLOPE * l0;
    l1 = (l1 >= 0.f) ? l1 : NEG_SLOPE * l1;
    l2 = (l2 >= 0.f) ? l2 : NEG_SLOPE * l2;
    l3 = (l3 >= 0.f) ? l3 : NEG_SLOPE * l3;
    // logits O(1): unnormalized exp safe; ratio is exact softmax
    float w0 = __expf(l0), w1 = __expf(l1), w2 = __expf(l2), w3 = __expf(l3);

    w4b[e] = make_uint2(pack_bf2(w0, w1), pack_bf2(w2, w3));
}

// ---------------------------------------------------------------------------
// exclusive prefix sum over count[] -> starts[], cursor[]
// ---------------------------------------------------------------------------
__global__ __launch_bounds__(256) void scan_a(const int* __restrict__ count,
                                              int* __restrict__ starts,
                                              int* __restrict__ blockSums) {
    __shared__ int sd[256];
    int t = threadIdx.x;
    int base = blockIdx.x * 1024 + t * 4;
    int c0 = (base + 0 < N_NODES) ? count[base + 0] : 0;
    int c1 = (base + 1 < N_NODES) ? count[base + 1] : 0;
    int c2 = (base + 2 < N_NODES) ? count[base + 2] : 0;
    int c3 = (base + 3 < N_NODES) ? count[base + 3] : 0;
    int s = c0 + c1 + c2 + c3;
    sd[t] = s;
    __syncthreads();
    for (int off = 1; off < 256; off <<= 1) {
        int v = (t >= off) ? sd[t - off] : 0;
        __syncthreads();
        sd[t] += v;
        __syncthreads();
    }
    int excl = sd[t] - s;
    if (base + 0 < N_NODES) starts[base + 0] = excl;
    if (base + 1 < N_NODES) starts[base + 1] = excl + c0;
    if (base + 2 < N_NODES) starts[base + 2] = excl + c0 + c1;
    if (base + 3 < N_NODES) starts[base + 3] = excl + c0 + c1 + c2;
    if (t == 255) blockSums[blockIdx.x] = sd[255];
}

__global__ __launch_bounds__(128) void scan_b(int* __restrict__ blockSums) {
    __shared__ int sd[128];
    int t = threadIdx.x;
    int v = (t < SCAN_BLOCKS) ? blockSums[t] : 0;
    sd[t] = v;
    __syncthreads();
    for (int off = 1; off < 128; off <<= 1) {
        int u = (t >= off) ? sd[t - off] : 0;
        __syncthreads();
        sd[t] += u;
        __syncthreads();
    }
    if (t < SCAN_BLOCKS) blockSums[t] = sd[t] - v;   // exclusive
}

__global__ __launch_bounds__(256) void scan_c(int* __restrict__ starts,
                                              int* __restrict__ cursor,
                                              const int* __restrict__ blockSums) {
    int off = blockSums[blockIdx.x];
    int base = blockIdx.x * 1024 + threadIdx.x * 4;
#pragma unroll
    for (int k = 0; k < 4; ++k) {
        int idx = base + k;
        if (idx < N_NODES) {
            int v = starts[idx] + off;
            starts[idx] = v;
            cursor[idx] = v;
        }
    }
    if (blockIdx.x == 0 && threadIdx.x == 0) starts[N_NODES] = N_EDGES;
}

// ---------------------------------------------------------------------------
// build_perm v2 — XCD-sliced scatter. Consecutive blocks go round-robin to
// XCDs, so slice = blockIdx&7 pins each dst-range's contiguous ~1.6 MB perm
// window to ONE XCD's L2: lines absorb all ~16 writes locally and write
// back once (R6 measured 100 MB WRITE for a 12.8 MB payload from cross-XCD
// line bouncing). Each XCD streams the full dst array (L3-served).
// Mapping assumption is perf-only: any slice<->XCD shuffle still covers
// every (chunk, slice) pair exactly once.
// ---------------------------------------------------------------------------
__global__ __launch_bounds__(256) void build_perm(
    const int* __restrict__ ei, int* __restrict__ cursor,
    uint2* __restrict__ perm_se) {
    int slice = blockIdx.x & 7;
    int e = (blockIdx.x >> 3) * 256 + threadIdx.x;
    if (e >= N_EDGES) return;
    int dn = ei[N_EDGES + e];
    if (dn < slice * BP_SLICE_N || dn >= (slice + 1) * BP_SLICE_N) return;
    int s = ei[e];
    int pos = atomicAdd(&cursor[dn], 1);
    perm_se[pos] = make_uint2((unsigned)s, (unsigned)e);
}

// ---------------------------------------------------------------------------
// gather v3: wave per node. Stage (src,e) coalesced; staging lanes fetch
// w4b[e] (8B, L2/L3-resident) into LDS; inner unroll-4 xh row gathers.
// ---------------------------------------------------------------------------
__global__ __launch_bounds__(256) void gather(
    const int* __restrict__ flag,
    const int* __restrict__ starts, const uint2* __restrict__ perm_se,
    const uint2* __restrict__ w4b, const unsigned short* __restrict__ xh,
    const float* __restrict__ gat_bias_f, const float* __restrict__ bias_f,
    void* __restrict__ out) {

    __shared__ int  sS[4][64];
    __shared__ uint2 sW[4][64];

    int t = threadIdx.x;
    int w = t >> 6, lane = t & 63, h = lane >> 4;
    int n = blockIdx.x * 4 + w;
    if (n >= N_NODES) return;
    int isf32 = *flag;

    int st = starts[n], en = starts[n + 1];
    float f0 = 0.f, f1 = 0.f, wsum = 0.f;

    for (int base = st; base < en; base += 64) {
        int cnt = en - base;
        if (cnt > 64) cnt = 64;
        __builtin_amdgcn_wave_barrier();
        if (lane < cnt) {
            uint2 se = perm_se[base + lane];
            sS[w][lane] = (int)se.x;
            sW[w][lane] = w4b[se.y];
        }
        __builtin_amdgcn_wave_barrier();
#pragma unroll 4
        for (int jj = 0; jj < cnt; ++jj) {
            int s = sS[w][jj];
            uint2 wb = sW[w][jj];
            unsigned hw = (h & 2) ? wb.y : wb.x;
            float wt = (h & 1) ? bf_hi(hw) : bf_lo(hw);
            unsigned xv = *(const unsigned*)(xh + ((size_t)s << 7) + 2 * lane);
            f0 += wt * bf_lo(xv);
            f1 += wt * bf_hi(xv);
            wsum += wt;
        }
    }

    float inv = (wsum > 0.f) ? 1.f / wsum : 0.f;
    float v0 = f0 * inv + gat_bias_f[2 * lane];
    float v1 = f1 * inv + gat_bias_f[2 * lane + 1];
    v0 += __shfl_xor(v0, 16); v0 += __shfl_xor(v0, 32);
    v1 += __shfl_xor(v1, 16); v1 += __shfl_xor(v1, 32);

    if (lane < 16) {
        int c = 2 * lane;
        float o0 = fmaxf(v0 * 0.25f + bias_f[c],     0.f);
        float o1 = fmaxf(v1 * 0.25f + bias_f[c + 1], 0.f);
        if (isf32) {
            *(float2*)((float*)out + (size_t)n * C_OUT + c) = make_float2(o0, o1);
        } else {
            unsigned p = ((unsigned)f2bf_rne(o1) << 16) | f2bf_rne(o0);
            *(unsigned*)((unsigned short*)out + (size_t)n * C_OUT + c) = p;
        }
    }
}

// ---------------------------------------------------------------------------
extern "C" void kernel_launch(void* const* d_in, const int* in_sizes, int n_in,
                              void* d_out, int out_size, void* d_ws, size_t ws_size,
                              hipStream_t stream) {
    const void* x         = d_in[0];
    const int*  ei        = (const int*)d_in[1];
    const void* edge_attr = d_in[2];
    const void* W         = d_in[3];
    const void* att_src   = d_in[4];
    const void* att_dst   = d_in[5];
    const void* W_edge    = d_in[6];
    const void* att_edge  = d_in[7];
    const void* gat_bias  = d_in[8];
    const void* bias      = d_in[9];

    char* ws = (char*)d_ws;
    size_t off = 0;
    auto align256 = [](size_t v) { return (v + 255) & ~(size_t)255; };

    unsigned short* xh = (unsigned short*)(ws + off);
    off = align256(off + (size_t)N_NODES * HC * sizeof(unsigned short));  // 25.6 MB
    float* a_src_w = (float*)(ws + off);
    off = align256(off + (size_t)N_NODES * HEADS * sizeof(float));
    float* a_dst_w = (float*)(ws + off);
    off = align256(off + (size_t)N_NODES * HEADS * sizeof(float));
    int* count = (int*)(ws + off);
    off = align256(off + (size_t)N_NODES * sizeof(int));
    int* starts = (int*)(ws + off);
    off = align256(off + (size_t)(N_NODES + 1) * sizeof(int));
    int* cursor = (int*)(ws + off);
    off = align256(off + (size_t)N_NODES * sizeof(int));
    int* blockSums = (int*)(ws + off);
    off = align256(off + (size_t)SCAN_BLOCKS * sizeof(int));
    uint2* w4b = (uint2*)(ws + off);
    off = align256(off + (size_t)N_EDGES * sizeof(uint2));                // 12.8 MB
    uint2* perm_se = (uint2*)(ws + off);
    off = align256(off + (size_t)N_EDGES * sizeof(uint2));                // 12.8 MB
    float* Wa = (float*)(ws + off);
    off = align256(off + 128 * sizeof(float));
    unsigned short* Wc = (unsigned short*)(ws + off);
    off = align256(off + (size_t)IN_CH * HC * sizeof(unsigned short));
    float* att_src_f = (float*)(ws + off);
    off = align256(off + 128 * sizeof(float));
    float* att_dst_f = (float*)(ws + off);
    off = align256(off + 128 * sizeof(float));
    float* gat_bias_f = (float*)(ws + off);
    off = align256(off + 128 * sizeof(float));
    float* bias_f = (float*)(ws + off);
    off = align256(off + 32 * sizeof(float));
    int* dflag = (int*)(ws + off);
    off = align256(off + sizeof(int));
    size_t need = off;

    if (ws_size < need) {
        report_err<<<1, 64, 0, stream>>>((unsigned short*)d_out, 1500.0f);
        return;
    }

    (void)hipGetLastError();

    detect<<<1, 256, 0, stream>>>((const unsigned*)x, dflag);
    prep_small<<<1, 256, 0, stream>>>(dflag, W, att_src, att_dst, W_edge,
                                      att_edge, gat_bias, bias,
                                      Wc, att_src_f, att_dst_f, gat_bias_f,
                                      bias_f, Wa);
    zero_ints<<<(N_NODES + 255) / 256, 256, 0, stream>>>(count, N_NODES);
    node_gemm<<<N_NODES / 32, 256, 0, stream>>>(dflag, x, Wc, att_src_f,
                                                att_dst_f, xh, a_src_w, a_dst_w);
    edge_w<<<(N_EDGES + 255) / 256, 256, 0, stream>>>(dflag, ei, edge_attr,
                                                      a_src_w, a_dst_w, Wa,
                                                      w4b, count);
    scan_a<<<SCAN_BLOCKS, 256, 0, stream>>>(count, starts, blockSums);
    scan_b<<<1, 128, 0, stream>>>(blockSums);
    scan_c<<<SCAN_BLOCKS, 256, 0, stream>>>(starts, cursor, blockSums);
    build_perm<<<BP_SLICES * BP_CHUNKS, 256, 0, stream>>>(ei, cursor, perm_se);
    gather<<<N_NODES / 4, 256, 0, stream>>>(dflag, starts, perm_se, w4b,
                                            xh, gat_bias_f, bias_f, d_out);

    hipError_t e = hipGetLastError();
    if (e != hipSuccess) {
        report_err<<<1, 64, 0, stream>>>((unsigned short*)d_out,
                                         1000.0f + (float)(int)e);
    }
}